// Round 1
// 197.758 us; speedup vs baseline: 1.0061x; 1.0061x over previous
//
#include <hip/hip_runtime.h>

// ---------------------------------------------------------------------------
// MultiHeadAttention: B=2, S=2048, E=1024, H=16, D=64, causal. fp32 I/O.
// R12: attention restructured.
//   - QBLK=128: each wave owns TWO 16-query groups (rows gb = q0+64g+16w),
//     so every staged 64-key K/V tile serves 128 queries (2x MFMA per
//     barrier; tile-iterations 16896 -> 8704).
//   - Split-K + attn_combine DELETED: one kernel, final normalize in-regs.
//   - Balanced dispatch map: 512 blocks (2/CU, all co-resident). Dispatch
//     half n>=256 gets qt2 = 15-qpre so co-resident pairs sum to 34 tiles;
//     bh chunked 4-per-XCD for K/V L2 locality (2MB/XCD).
//   - P pack via v_cvt_pk_bf16_f32 (1 inst / 2 elems) instead of 5-op f2bf.
// GEMMs / prep unchanged from R11b (m97-structure, single-barrier dbuf GLL).
// ---------------------------------------------------------------------------

typedef __attribute__((ext_vector_type(8))) short short8;
typedef __attribute__((ext_vector_type(4))) short short4v;
typedef __attribute__((ext_vector_type(4))) float floatx4;

#define NB 2
#define SEQ 2048
#define EMB 1024
#define NH 16
#define HD 64
#define M_ROWS (NB * SEQ)        // 4096
#define N_QKV (3 * EMB)          // 3072

#define GLL(g, l) __builtin_amdgcn_global_load_lds( \
    (const __attribute__((address_space(1))) void*)(g), \
    (__attribute__((address_space(3))) void*)(l), 16, 0, 0)

#if defined(__HIP_DEVICE_COMPILE__)
#define MFMA16K16(A, B, C) __builtin_amdgcn_mfma_f32_16x16x16bf16_1k(A, B, C, 0, 0, 0)
#else
#define MFMA16K16(A, B, C) (C)   // host pass parses but never executes this
#endif

static __device__ __forceinline__ unsigned short f2bf(float f) {
    union { float f; unsigned int u; } v; v.f = f;
    unsigned int r = v.u + 0x7FFFu + ((v.u >> 16) & 1u);
    return (unsigned short)(r >> 16);
}
static __device__ __forceinline__ float bf2f(unsigned short h) {
    union { unsigned int u; float f; } v; v.u = ((unsigned int)h) << 16;
    return v.f;
}

// packed f32x2 -> bf16x2 (RNE) in one HW instruction
static __device__ __forceinline__ unsigned int cvt_pk_bf16(float lo, float hi) {
#if defined(__HIP_DEVICE_COMPILE__)
    unsigned int r;
    asm("v_cvt_pk_bf16_f32 %0, %1, %2" : "=v"(r) : "v"(lo), "v"(hi));
    return r;
#else
    (void)lo; (void)hi; return 0u;  // host pass never executes
#endif
}
static __device__ __forceinline__ short4v pack4bf(float a, float b, float c, float d) {
    union { unsigned int u[2]; short4v s; } pu;
    pu.u[0] = cvt_pk_bf16(a, b);
    pu.u[1] = cvt_pk_bf16(c, d);
    return pu.s;
}

// Fused prep: z=0 transpose W_qkv, z=1 transpose W_o, z=2 convert x -> bf16.
__global__ void prep(const float* __restrict__ x,
                     const float* __restrict__ Wqkv, const float* __restrict__ Wo,
                     unsigned short* __restrict__ x_bf,
                     unsigned short* __restrict__ wqkvT, unsigned short* __restrict__ woT) {
    __shared__ unsigned short tile[32][33];
    int z = blockIdx.z;
    int tx = threadIdx.x, ty = threadIdx.y;
    if (z == 2) {
        int id = ((int)blockIdx.y * 96 + (int)blockIdx.x) * 256 + ty * 32 + tx;
        const int n4 = M_ROWS * EMB / 4;
        for (int i = id; i < n4; i += 96 * 32 * 256) {
            float4 v = ((const float4*)x)[i];
            unsigned long long p = (unsigned long long)f2bf(v.x)
                | ((unsigned long long)f2bf(v.y) << 16)
                | ((unsigned long long)f2bf(v.z) << 32)
                | ((unsigned long long)f2bf(v.w) << 48);
            ((unsigned long long*)x_bf)[i] = p;
        }
        return;
    }
    int C = z ? EMB : N_QKV;
    if ((int)blockIdx.x * 32 >= C) return;
    const float* in = z ? Wo : Wqkv;
    unsigned short* out = z ? woT : wqkvT;
    const int R = EMB;
    int c0 = blockIdx.x * 32, r0 = blockIdx.y * 32;
    #pragma unroll
    for (int j = 0; j < 4; ++j)
        tile[ty + j * 8][tx] = f2bf(in[(size_t)(r0 + ty + j * 8) * C + c0 + tx]);
    __syncthreads();
    #pragma unroll
    for (int j = 0; j < 4; ++j)
        out[(size_t)(c0 + ty + j * 8) * R + r0 + tx] = tile[tx][ty + j * 8];
}

// ---------------------------------------------------------------------------
// QKV GEMM: single-barrier dbuf GLL K-loop + LDS-roundtrip coalesced epilogue.
// Q,K -> [B,H,S,D]; V -> [B,H,D,S].
// ---------------------------------------------------------------------------
#define CTS 130   // C-tile LDS stride (shorts), pad 2

__global__ __launch_bounds__(256) void qkv_gemm(
    const unsigned short* __restrict__ A,    // x_bf [4096][1024]
    const unsigned short* __restrict__ Bt,   // W_qkv^T [3072][1024] bf16
    const float* __restrict__ bias,          // [3072] fp32
    unsigned short* __restrict__ qb, unsigned short* __restrict__ kb,
    unsigned short* __restrict__ vb)         // vb: [B,H,D,S]
{
    const int K = EMB;
    __shared__ __align__(16) unsigned short smem[128 * CTS];

    int t = threadIdx.x;
    int m0 = blockIdx.y * 128;
    int n0 = blockIdx.x * 128;
    int w = t >> 6, lane = t & 63, quad = lane >> 4, lcol = lane & 15;
    int wr = w >> 1, wc = w & 1;

    floatx4 zero = {0.f, 0.f, 0.f, 0.f};
    floatx4 acc[4][4];
    #pragma unroll
    for (int i = 0; i < 4; ++i)
        #pragma unroll
        for (int j = 0; j < 4; ++j) acc[i][j] = zero;

    const unsigned short* a0 = A  + (size_t)(m0 + (t >> 2)) * K + ((t & 3) << 3);
    const unsigned short* b0 = Bt + (size_t)(n0 + (t >> 2)) * K + ((t & 3) << 3);
    unsigned short* la = &smem[t << 3];          // + buf*8192 ; Bs at +4096

    GLL(a0, la);
    GLL(a0 + 64 * K, la + 2048);
    GLL(b0, la + 4096);
    GLL(b0 + 64 * K, la + 6144);

    for (int k0 = 0; k0 < K; k0 += 32) {
        int cur = (k0 >> 5) & 1, nxt = cur ^ 1;
        __syncthreads();                         // drains cur's staging loads
        if (k0 + 32 < K) {                       // prefetch nxt AFTER barrier
            GLL(a0 + k0 + 32, la + nxt * 8192);
            GLL(a0 + 64 * K + k0 + 32, la + nxt * 8192 + 2048);
            GLL(b0 + k0 + 32, la + nxt * 8192 + 4096);
            GLL(b0 + 64 * K + k0 + 32, la + nxt * 8192 + 6144);
        }
        const unsigned short* As = &smem[cur * 8192];
        const unsigned short* Bs = As + 4096;
        short8 af[4], bfm[4];
        #pragma unroll
        for (int i = 0; i < 4; ++i)
            af[i] = *(const short8*)(&As[(wr * 64 + i * 16 + lcol) * 32 + quad * 8]);
        #pragma unroll
        for (int j = 0; j < 4; ++j)
            bfm[j] = *(const short8*)(&Bs[(wc * 64 + j * 16 + lcol) * 32 + quad * 8]);
        #pragma unroll
        for (int i = 0; i < 4; ++i)
            #pragma unroll
            for (int j = 0; j < 4; ++j)
                acc[i][j] = __builtin_amdgcn_mfma_f32_16x16x32_bf16(af[i], bfm[j], acc[i][j], 0, 0, 0);
    }

    // ---- epilogue: bias + bf16 into LDS C-tile, then coalesced streams ----
    bool isV = (n0 >= 2 * EMB);
    __syncthreads();
    #pragma unroll
    for (int i = 0; i < 4; ++i) {
        int row0 = wr * 64 + i * 16 + quad * 4;
        #pragma unroll
        for (int j = 0; j < 4; ++j) {
            int col = wc * 64 + j * 16 + lcol;
            float bv = bias[n0 + col];
            #pragma unroll
            for (int r = 0; r < 4; ++r) {
                unsigned short hv = f2bf(acc[i][j][r] + bv);
                if (isV) smem[col * CTS + row0 + r] = hv;   // [feature][token]
                else     smem[(row0 + r) * CTS + col] = hv; // [token][feature]
            }
        }
    }
    __syncthreads();

    int b = m0 >> 11, s0 = m0 & 2047;
    int hbase = (n0 & 1023) >> 6;
    if (!isV) {
        unsigned short* dst = (n0 >= EMB) ? kb : qb;
        #pragma unroll
        for (int it = 0; it < 8; ++it) {
            int job = it * 32 + (t >> 3);
            int tok = job & 127, hh = job >> 7;
            int chunk = t & 7;
            short8 vv = *(const short8*)(&smem[tok * CTS + hh * 64 + chunk * 8]);
            size_t g = ((size_t)((b * NH + hbase + hh) * SEQ + s0 + tok)) * HD + chunk * 8;
            *(short8*)(&dst[g]) = vv;
        }
    } else {
        #pragma unroll
        for (int it = 0; it < 8; ++it) {
            int job = it * 32 + (t >> 3);
            int f = job & 127, half = job >> 7;
            int chunk = (t & 7) + half * 8;
            short8 vv = *(const short8*)(&smem[f * CTS + chunk * 8]);
            int h = hbase + (f >> 6), d = f & 63;
            size_t g = ((size_t)((b * NH + h) * HD + d)) * SEQ + s0 + chunk * 8;
            *(short8*)(&vb[g]) = vv;
        }
    }
}

// ---------------------------------------------------------------------------
// Fused causal flash attention, QBLK=128, no split-K.
// Block: 256 threads (4 waves). Wave w owns query groups gb = q0+64g+16w,
// g=0,1. Per 64-key tile: S^T = K*Q^T (2 groups x 8 MFMA 16x16x32),
// P^T packed bf16 via cvt_pk -> direct 16x16x16 B-frag, O^T += V^T*P^T
// (V frags read once, used by both groups). l via ones-MFMA. Final
// normalize + bf16 write for all queries (no partials, no combine).
// ---------------------------------------------------------------------------
__global__ __launch_bounds__(256) void attn_fused(
    const unsigned short* __restrict__ Q,   // [B*H][S][D]
    const unsigned short* __restrict__ Kk,  // [B*H][S][D]
    const unsigned short* __restrict__ Vt,  // [B*H][D][S]
    unsigned short* __restrict__ Out)       // [b][s][h*64+d]
{
    __shared__ __align__(16) unsigned short Ks[2][64 * 64];
    __shared__ __align__(16) unsigned short Vs[2][64 * 64];

    // ---- dispatch map: balance + XCD locality ----
    // hw id n in [0,512). xcd = n&7 (presumed round-robin); each XCD gets
    // bh in [xcd*4, xcd*4+4) -> 2MB K/V in its L2. Halves n<256 / n>=256
    // get qt2 = qpre / 15-qpre so co-resident pairs total 34 tiles.
    int n = (int)blockIdx.y * 16 + (int)blockIdx.x;   // dispatch order
    int hi = n >> 8;
    int j = n & 255;
    int idx = j >> 3;                 // 0..31
    int bh = (j & 7) * 4 + (idx & 3); // 0..31
    int qpre = idx >> 2;              // 0..7
    int qt2 = hi ? (15 - qpre) : qpre;

    int q0 = qt2 * 128;
    int ktEnd = 2 * (qt2 + 1);        // keys [0, 128*(qt2+1)) in 64-key tiles

    int t = threadIdx.x;
    int w = t >> 6, lane = t & 63, quad = lane >> 4, lcol = lane & 15;
    const size_t hoff = (size_t)bh * SEQ * HD;
    const float SC = 0.18033688011112043f;   // (1/sqrt(64)) * log2(e)

    // Q strips (B-operand), two groups per wave
    short8 aq[2][2];
    #pragma unroll
    for (int g = 0; g < 2; ++g) {
        const unsigned short* qp = Q + hoff
            + (size_t)(q0 + g * 64 + 16 * w + lcol) * HD + quad * 8;
        aq[g][0] = *(const short8*)qp;
        aq[g][1] = *(const short8*)(qp + 32);
    }

    int srow = t >> 3;                       // 0..31
    int ss   = (t & 7) ^ (srow & 7);         // pre-swizzled global source
    const unsigned short* kgl = Kk + hoff + (size_t)srow * HD + ss * 8;
    const unsigned short* vgl = Vt + hoff + (size_t)srow * SEQ + ss * 8;
    unsigned short* kld = &Ks[0][t * 8];
    unsigned short* vld = &Vs[0][t * 8];

    floatx4 zero = {0.f, 0.f, 0.f, 0.f};
    floatx4 O[2][4];                 // O^T: row=d(quad*4+r in td*16), col=query lcol
    floatx4 lacc[2];                 // all rows = l[query lcol]
    #pragma unroll
    for (int g = 0; g < 2; ++g) {
        lacc[g] = zero;
        #pragma unroll
        for (int td = 0; td < 4; ++td) O[g][td] = zero;
    }

    short4v ones4;
    #pragma unroll
    for (int jj = 0; jj < 4; ++jj) ones4[jj] = (short)0x3F80;  // bf16 1.0

    {   // prologue: stage tile 0 into buf 0
        GLL(kgl, kld);
        GLL(kgl + (size_t)32 * HD, kld + 2048);
        GLL(vgl, vld);
        GLL(vgl + (size_t)32 * SEQ, vld + 2048);
    }

    int sx0 = (quad ^ (lcol & 7)) << 3;
    int sx1 = sx0 ^ 32;

    for (int kt = 0; kt < ktEnd; ++kt) {
        int cur = kt & 1, nxt = cur ^ 1;
        __syncthreads();                     // drains tile-kt staging loads
        if (kt + 1 < ktEnd) {
            int k0 = (kt + 1) * 64;
            GLL(kgl + (size_t)k0 * HD, kld + nxt * 4096);
            GLL(kgl + (size_t)(k0 + 32) * HD, kld + nxt * 4096 + 2048);
            GLL(vgl + k0, vld + nxt * 4096);
            GLL(vgl + (size_t)32 * SEQ + k0, vld + nxt * 4096 + 2048);
        }

        const unsigned short* ksr = &Ks[cur][0];
        const unsigned short* vsr = &Vs[cur][0];
        short8 bk0[4], bk1[4];
        #pragma unroll
        for (int tc = 0; tc < 4; ++tc) {
            int rb = (tc * 16 + lcol) << 6;
            bk0[tc] = *(const short8*)(ksr + rb + sx0);
            bk1[tc] = *(const short8*)(ksr + rb + sx1);
        }

        short4v pk[2][4];
        bool act[2];
        #pragma unroll
        for (int g = 0; g < 2; ++g) {
            const int gb = q0 + g * 64 + 16 * w;     // wave-uniform
            act[g] = (kt * 64 <= gb + 15);
            if (act[g]) {
                // S^T = K * Q^T  (A = K tile rows=keys, B = Q strip cols=queries)
                floatx4 sacc[4];
                #pragma unroll
                for (int tc = 0; tc < 4; ++tc) {
                    sacc[tc] = __builtin_amdgcn_mfma_f32_16x16x32_bf16(bk0[tc], aq[g][0], zero, 0, 0, 0);
                    sacc[tc] = __builtin_amdgcn_mfma_f32_16x16x32_bf16(bk1[tc], aq[g][1], sacc[tc], 0, 0, 0);
                }
                if (kt * 64 + 63 > gb) {             // diagonal tile: mask
                    int qrow = gb + lcol;
                    #pragma unroll
                    for (int tc = 0; tc < 4; ++tc) {
                        float p[4];
                        #pragma unroll
                        for (int r = 0; r < 4; ++r) {
                            float e = __builtin_amdgcn_exp2f(sacc[tc][r] * SC);
                            p[r] = (kt * 64 + tc * 16 + quad * 4 + r > qrow) ? 0.f : e;
                        }
                        pk[g][tc] = pack4bf(p[0], p[1], p[2], p[3]);
                    }
                } else {
                    #pragma unroll
                    for (int tc = 0; tc < 4; ++tc) {
                        pk[g][tc] = pack4bf(
                            __builtin_amdgcn_exp2f(sacc[tc][0] * SC),
                            __builtin_amdgcn_exp2f(sacc[tc][1] * SC),
                            __builtin_amdgcn_exp2f(sacc[tc][2] * SC),
                            __builtin_amdgcn_exp2f(sacc[tc][3] * SC));
                    }
                }
            }
        }

        // O^T += V^T * P^T  -- V frags read ONCE, consumed by both groups
        #pragma unroll
        for (int td = 0; td < 4; ++td) {
            short4v va[4];
            #pragma unroll
            for (int tc = 0; tc < 4; ++tc) {
                int seg = ((tc << 1) + (quad >> 1)) ^ (lcol & 7);
                va[tc] = *(const short4v*)(vsr + ((td * 16 + lcol) << 6) + (seg << 3) + ((quad & 1) << 2));
            }
            if (act[0]) {
                #pragma unroll
                for (int tc = 0; tc < 4; ++tc)
                    O[0][td] = MFMA16K16(va[tc], pk[0][tc], O[0][td]);
            }
            if (act[1]) {
                #pragma unroll
                for (int tc = 0; tc < 4; ++tc)
                    O[1][td] = MFMA16K16(va[tc], pk[1][tc], O[1][td]);
            }
        }
        // l[q] += sum_key P^T[key][q]
        #pragma unroll
        for (int g = 0; g < 2; ++g) {
            if (act[g]) {
                #pragma unroll
                for (int tc = 0; tc < 4; ++tc)
                    lacc[g] = MFMA16K16(ones4, pk[g][tc], lacc[g]);
            }
        }
    }

    // ---- final normalize + write (all queries final; no partials) ----
    int b = bh >> 4, h = bh & 15;
    #pragma unroll
    for (int g = 0; g < 2; ++g) {
        int qrow = q0 + g * 64 + 16 * w + lcol;
        float inv = 1.0f / lacc[g][0];
        size_t obase = ((size_t)b * SEQ + qrow) * EMB + (size_t)h * HD + quad * 4;
        #pragma unroll
        for (int td = 0; td < 4; ++td) {
            short4v ov;
            #pragma unroll
            for (int r = 0; r < 4; ++r) ov[r] = (short)f2bf(O[g][td][r] * inv);
            *(short4v*)(&Out[obase + td * 16]) = ov;
        }
    }
}

// ---------------------------------------------------------------------------
// Output projection: single-barrier dbuf GLL K-loop. fp32 bias, fp32 out.
// ---------------------------------------------------------------------------
__global__ __launch_bounds__(256) void oproj_gemm(
    const unsigned short* __restrict__ A,    // [4096][1024] bf16
    const unsigned short* __restrict__ Bt,   // W_o^T [1024][1024] bf16
    const float* __restrict__ bias,          // [1024] fp32
    float* __restrict__ Cout)                // [4096][1024] fp32
{
    const int K = EMB;
    __shared__ __align__(16) unsigned short smem[2 * 8192];
    int t = threadIdx.x;
    int m0 = blockIdx.y * 128;
    int n0 = blockIdx.x * 128;
    int w = t >> 6, lane = t & 63, quad = lane >> 4, lcol = lane & 15;
    int wr = w >> 1, wc = w & 1;

    floatx4 zero = {0.f, 0.f, 0.f, 0.f};
    floatx4 acc[4][4];
    #pragma unroll
    for (int i = 0; i < 4; ++i)
        #pragma unroll
        for (int j = 0; j < 4; ++j) acc[i][j] = zero;

    const unsigned short* a0 = A  + (size_t)(m0 + (t >> 2)) * K + ((t & 3) << 3);
    const unsigned short* b0 = Bt + (size_t)(n0 + (t >> 2)) * K + ((t & 3) << 3);
    unsigned short* la = &smem[t << 3];

    GLL(a0, la);
    GLL(a0 + 64 * K, la + 2048);
    GLL(b0, la + 4096);
    GLL(b0 + 64 * K, la + 6144);

    for (int k0 = 0; k0 < K; k0 += 32) {
        int cur = (k0 >> 5) & 1, nxt = cur ^ 1;
        __syncthreads();
        if (k0 + 32 < K) {
            GLL(a0 + k0 + 32, la + nxt * 8192);
            GLL(a0 + 64 * K + k0 + 32, la + nxt * 8192 + 2048);
            GLL(b0 + k0 + 32, la + nxt * 8192 + 4096);
            GLL(b0 + 64 * K + k0 + 32, la + nxt * 8192 + 6144);
        }
        const unsigned short* As = &smem[cur * 8192];
        const unsigned short* Bs = As + 4096;
        short8 af[4], bfm[4];
        #pragma unroll
        for (int i = 0; i < 4; ++i)
            af[i] = *(const short8*)(&As[(wr * 64 + i * 16 + lcol) * 32 + quad * 8]);
        #pragma unroll
        for (int j = 0; j < 4; ++j)
            bfm[j] = *(const short8*)(&Bs[(wc * 64 + j * 16 + lcol) * 32 + quad * 8]);
        #pragma unroll
        for (int i = 0; i < 4; ++i)
            #pragma unroll
            for (int j = 0; j < 4; ++j)
                acc[i][j] = __builtin_amdgcn_mfma_f32_16x16x32_bf16(af[i], bfm[j], acc[i][j], 0, 0, 0);
    }

    #pragma unroll
    for (int i = 0; i < 4; ++i) {
        int m = m0 + wr * 64 + i * 16 + quad * 4;
        #pragma unroll
        for (int j = 0; j < 4; ++j) {
            int n = n0 + wc * 64 + j * 16 + lcol;
            float bv = bias[n];
            #pragma unroll
            for (int r = 0; r < 4; ++r)
                Cout[(size_t)(m + r) * EMB + n] = acc[i][j][r] + bv;
        }
    }
}

// ---------------------------------------------------------------------------
extern "C" void kernel_launch(void* const* d_in, const int* in_sizes, int n_in,
                              void* d_out, int out_size, void* d_ws, size_t ws_size,
                              hipStream_t stream) {
    (void)in_sizes; (void)n_in; (void)out_size; (void)ws_size;
    char* ws = (char*)d_ws;
    const size_t OFF_X     = 0;                                      // 8 MB
    const size_t OFF_WQKVT = OFF_X     + (size_t)M_ROWS * EMB * 2;   // 6 MB
    const size_t OFF_WOT   = OFF_WQKVT + (size_t)N_QKV * EMB * 2;    // 2 MB
    const size_t OFF_Q     = OFF_WOT   + (size_t)EMB * EMB * 2;      // 8 MB
    const size_t OFF_K     = OFF_Q     + (size_t)M_ROWS * EMB * 2;   // 8 MB
    const size_t OFF_V     = OFF_K     + (size_t)M_ROWS * EMB * 2;   // 8 MB
    const size_t OFF_ATTN  = OFF_V     + (size_t)M_ROWS * EMB * 2;   // 8 MB

    const float* x    = (const float*)d_in[0];
    const float* Wqkv = (const float*)d_in[1];
    const float* bqkv = (const float*)d_in[2];
    const float* Wo   = (const float*)d_in[3];
    const float* bo   = (const float*)d_in[4];

    unsigned short* x_bf  = (unsigned short*)(ws + OFF_X);
    unsigned short* wqkvT = (unsigned short*)(ws + OFF_WQKVT);
    unsigned short* woT   = (unsigned short*)(ws + OFF_WOT);
    unsigned short* qb    = (unsigned short*)(ws + OFF_Q);
    unsigned short* kb    = (unsigned short*)(ws + OFF_K);
    unsigned short* vb    = (unsigned short*)(ws + OFF_V);    // [B,H,D,S]
    unsigned short* attn  = (unsigned short*)(ws + OFF_ATTN);

    prep<<<dim3(96, 32, 3), dim3(32, 8), 0, stream>>>(x, Wqkv, Wo, x_bf, wqkvT, woT);

    qkv_gemm<<<dim3(N_QKV / 128, M_ROWS / 128), 256, 0, stream>>>(x_bf, wqkvT, bqkv, qb, kb, vb);
    attn_fused<<<dim3(16, NB * NH), 256, 0, stream>>>(qb, kb, vb, attn);
    oproj_gemm<<<dim3(EMB / 128, M_ROWS / 128), 256, 0, stream>>>(attn, woT, bo, (float*)d_out);
}